// Round 1
// baseline (4958.282 us; speedup 1.0000x reference)
//
#include <hip/hip_runtime.h>
#include <math.h>

#define LIDX(jj) ((jj) + (((jj) >> 4) << 2))

// ---------- Laplacian pipeline ----------

// one block per row (3 rows); stats[r] = 1/(std_ddof1 + 0.01)
__global__ __launch_bounds__(256) void k_rowstats(const float* __restrict__ X, int N,
                                                  float* __restrict__ stats) {
    int r = blockIdx.x;
    const float* row = X + (size_t)r * N;
    double s = 0.0, ss = 0.0;
    for (int i = threadIdx.x; i < N; i += 256) { double v = row[i]; s += v; ss += v * v; }
    __shared__ double sh_s[256], sh_ss[256];
    sh_s[threadIdx.x] = s; sh_ss[threadIdx.x] = ss; __syncthreads();
    for (int off = 128; off > 0; off >>= 1) {
        if (threadIdx.x < off) { sh_s[threadIdx.x] += sh_s[threadIdx.x + off];
                                 sh_ss[threadIdx.x] += sh_ss[threadIdx.x + off]; }
        __syncthreads();
    }
    if (threadIdx.x == 0) {
        double mean = sh_s[0] / N;
        double var = (sh_ss[0] - mean * sh_s[0]) / (N - 1);
        if (var < 0.0) var = 0.0;
        stats[r] = 1.0f / ((float)sqrt(var) + 0.01f);
    }
}

__global__ __launch_bounds__(256) void k_xnsq(const float* __restrict__ X,
                                              const float* __restrict__ stats,
                                              float* __restrict__ Xn, float* __restrict__ sq, int N) {
    int i = blockIdx.x * 256 + threadIdx.x;
    if (i >= N) return;
    float s = 0.f;
    #pragma unroll
    for (int k = 0; k < 3; k++) {
        float v = X[(size_t)k * N + i] * stats[k];
        Xn[(size_t)k * N + i] = v;
        s += v * v;
    }
    sq[i] = s;
}

// W[i,j] = exp(-max(sq_i+sq_j-2<xi,xj>,0)/10)
__global__ __launch_bounds__(256) void k_we(const float* __restrict__ Xn,
                                            const float* __restrict__ sq,
                                            float* __restrict__ W, int N) {
    int i = blockIdx.y;
    int j = blockIdx.x * 256 + threadIdx.x;
    float a0 = Xn[i], a1 = Xn[N + i], a2 = Xn[2 * N + i];
    float si = sq[i];
    float b0 = Xn[j], b1 = Xn[N + j], b2 = Xn[2 * N + j];
    float D = si + sq[j] - 2.f * (a0 * b0 + a1 * b1 + a2 * b2);
    D = fmaxf(D, 0.f);
    W[(size_t)i * N + j] = exp2f(-D * 0.14426950408889634f); // log2(e)/10
}

// d[i] = sum_j W[i,j]  (== column sum by exact symmetry)
__global__ __launch_bounds__(256) void k_rowsum(const float* __restrict__ W,
                                                float* __restrict__ d, int N) {
    int i = blockIdx.x;
    const float* row = W + (size_t)i * N;
    float s = 0.f;
    for (int j = threadIdx.x; j < N; j += 256) s += row[j];
    __shared__ float sh[256];
    sh[threadIdx.x] = s; __syncthreads();
    for (int off = 128; off > 0; off >>= 1) {
        if (threadIdx.x < off) sh[threadIdx.x] += sh[threadIdx.x + off];
        __syncthreads();
    }
    if (threadIdx.x == 0) d[i] = sh[0];
}

// L[i,j] = M_i*M_j*((i==j)?d_j:0 - W[i,j]) + (i==j)*(1-M_j), in place
__global__ __launch_bounds__(256) void k_finalize(float* __restrict__ W,
                                                  const float* __restrict__ d,
                                                  const float* __restrict__ m, int N) {
    size_t idx = (size_t)blockIdx.x * 256 + threadIdx.x;
    int i = (int)(idx / N), j = (int)(idx % N);
    float w = W[idx];
    float l = ((i == j) ? d[j] : 0.f) - w;
    l = m[i] * m[j] * l;
    if (i == j) l += 1.f - m[j];
    W[idx] = l;
}

// ---------- GEMM: y[c,j] = sum_i x[c,i] * L[i,j], split-K over grid.z ----------

__global__ __launch_bounds__(256) void k_matmul(const float* __restrict__ x,
                                                const float* __restrict__ L,
                                                float* __restrict__ yp, int C, int N, int chunk) {
    __shared__ float Ls[32][128];
    __shared__ float xsT[32][36];
    int t = threadIdx.x;
    int jl = t & 63;
    int cg = t >> 6;
    int j0 = blockIdx.x * 128;
    int c0 = blockIdx.y * 32;
    int i_begin = blockIdx.z * chunk;
    float acc[8][2];
    #pragma unroll
    for (int r = 0; r < 8; r++) { acc[r][0] = 0.f; acc[r][1] = 0.f; }

    for (int i0 = i_begin; i0 < i_begin + chunk; i0 += 32) {
        #pragma unroll
        for (int rr = 0; rr < 4; rr++) {
            int idx = rr * 256 + t;
            int row = idx >> 5;
            int col = (idx & 31) << 2;
            *(float4*)(&Ls[row][col]) = *(const float4*)(L + (size_t)(i0 + row) * N + j0 + col);
        }
        #pragma unroll
        for (int ll = 0; ll < 4; ll++) {
            int idx = ll * 256 + t;
            int cc = idx >> 5;
            int ii = idx & 31;
            xsT[ii][cc] = x[(size_t)(c0 + cc) * N + i0 + ii];
        }
        __syncthreads();
        #pragma unroll
        for (int ii = 0; ii < 32; ii++) {
            float4 a0 = *(const float4*)(&xsT[ii][cg * 8]);
            float4 a1 = *(const float4*)(&xsT[ii][cg * 8 + 4]);
            float2 lv = *(const float2*)(&Ls[ii][jl * 2]);
            acc[0][0] += a0.x * lv.x; acc[0][1] += a0.x * lv.y;
            acc[1][0] += a0.y * lv.x; acc[1][1] += a0.y * lv.y;
            acc[2][0] += a0.z * lv.x; acc[2][1] += a0.z * lv.y;
            acc[3][0] += a0.w * lv.x; acc[3][1] += a0.w * lv.y;
            acc[4][0] += a1.x * lv.x; acc[4][1] += a1.x * lv.y;
            acc[5][0] += a1.y * lv.x; acc[5][1] += a1.y * lv.y;
            acc[6][0] += a1.z * lv.x; acc[6][1] += a1.z * lv.y;
            acc[7][0] += a1.w * lv.x; acc[7][1] += a1.w * lv.y;
        }
        __syncthreads();
    }
    float* yo = yp + (size_t)blockIdx.z * C * N;
    #pragma unroll
    for (int r = 0; r < 8; r++) {
        int c = c0 + cg * 8 + r;
        *(float2*)(yo + (size_t)c * N + j0 + jl * 2) = make_float2(acc[r][0], acc[r][1]);
    }
}

__global__ __launch_bounds__(256) void k_reduce(const float* __restrict__ yp,
                                                float* __restrict__ y, int parts, size_t total) {
    size_t idx = (size_t)blockIdx.x * 256 + threadIdx.x;
    if (idx >= total) return;
    float s = 0.f;
    for (int p = 0; p < parts; p++) s += yp[(size_t)p * total + idx];
    y[idx] = s;
}

// ---------- fused conv(9-tap) + mask + instance-norm + relu + residual ----------
// one block per output channel o. CH = columns per thread (4/8/16).
template <int CH>
__global__ __launch_bounds__(256) void k_conv_in(const float* __restrict__ y,
                                                 const float* __restrict__ Kw,
                                                 const float* __restrict__ m,
                                                 const float* __restrict__ res,
                                                 float* __restrict__ xout,
                                                 int C_in, int C_out, int N, int transpose) {
    __shared__ float row[5200];     // swizzled row buffer, cols [-4, N+4)
    __shared__ float red[256], red2[256];
    int o = blockIdx.x;
    int t = threadIdx.x;
    int A = N / CH;
    bool active = (t < A);
    int j0 = t * CH;

    float zacc[CH];
    #pragma unroll
    for (int l = 0; l < CH; l++) zacc[l] = 0.f;

    // zero halo: buffer index bi = col + 4; bi in [0,4) and [N+4,N+8)
    if (t < 4) row[LIDX(t)] = 0.f;
    else if (t < 8) row[LIDX(N + t)] = 0.f;

    for (int i = 0; i < C_in; i++) {
        __syncthreads();
        for (int jj = t; jj < N; jj += 256) row[LIDX(jj + 4)] = y[(size_t)i * N + jj];
        __syncthreads();

        float wt[9];
        if (!transpose) {
            #pragma unroll
            for (int tp = 0; tp < 9; tp++) wt[tp] = Kw[((size_t)o * C_in + i) * 9 + tp];
        } else {
            #pragma unroll
            for (int tp = 0; tp < 9; tp++) wt[tp] = Kw[((size_t)i * C_out + o) * 9 + (8 - tp)];
        }

        if (active) {
            float w[CH + 8];
            #pragma unroll
            for (int q = 0; q < CH / 4 + 2; q++) {
                float4 v = *(const float4*)(&row[LIDX(j0 + 4 * q)]);
                w[4 * q + 0] = v.x; w[4 * q + 1] = v.y; w[4 * q + 2] = v.z; w[4 * q + 3] = v.w;
            }
            #pragma unroll
            for (int l = 0; l < CH; l++) {
                float z = 0.f;
                #pragma unroll
                for (int tp = 0; tp < 9; tp++) z += w[l + tp] * wt[tp];
                zacc[l] += z;
            }
        }
    }

    // mask + instance-norm stats
    float zm[CH];
    #pragma unroll
    for (int l = 0; l < CH; l++) zm[l] = 0.f;
    float s = 0.f, ss = 0.f;
    if (active) {
        #pragma unroll
        for (int l = 0; l < CH; l++) {
            float v = zacc[l] * m[j0 + l];
            zm[l] = v; s += v; ss += v * v;
        }
    }
    red[t] = s; red2[t] = ss;
    __syncthreads();
    for (int off = 128; off > 0; off >>= 1) {
        if (t < off) { red[t] += red[t + off]; red2[t] += red2[t + off]; }
        __syncthreads();
    }
    float mean = red[0] / N;
    float var = red2[0] / N - mean * mean;
    var = fmaxf(var, 0.f);
    float rs = rsqrtf(var + 1e-5f);

    if (active) {
        #pragma unroll
        for (int l = 0; l < CH; l++) {
            float v = (zm[l] - mean) * rs;
            v = fmaxf(v, 0.f);
            if (res) v += res[(size_t)o * N + j0 + l];
            xout[(size_t)o * N + j0 + l] = v;
        }
    }
}

// ---------- pool / repeat ----------

__global__ __launch_bounds__(256) void k_pool(const float* __restrict__ in,
                                              float* __restrict__ out, int rows, int Nin) {
    int No = Nin >> 1;
    int idx = blockIdx.x * 256 + threadIdx.x;
    if (idx >= rows * No) return;
    int r = idx / No, i = idx % No;
    const float* p = in + (size_t)r * Nin;
    float a = (i > 0) ? p[2 * i - 1] : 0.f;
    float b = p[2 * i];
    float c = p[2 * i + 1];
    out[(size_t)r * No + i] = (a + b + c) * (1.f / 3.f);
}

__global__ __launch_bounds__(256) void k_repeat(const float* __restrict__ in,
                                                float* __restrict__ out, int rows, int Nin) {
    int idx = blockIdx.x * 256 + threadIdx.x;
    if (idx >= rows * Nin) return;
    int r = idx / Nin, i = idx % Nin;
    float v = in[(size_t)r * Nin + i];
    out[(size_t)r * 2 * Nin + 2 * i] = v;
    out[(size_t)r * 2 * Nin + 2 * i + 1] = v;
}

// ---------- host ----------

extern "C" void kernel_launch(void* const* d_in, const int* in_sizes, int n_in,
                              void* d_out, int out_size, void* d_ws, size_t ws_size,
                              hipStream_t stream) {
    (void)in_sizes; (void)n_in; (void)out_size; (void)ws_size;
    const float* x_in = (const float*)d_in[0];
    const float* X0 = (const float*)d_in[1];
    const float* m0 = (const float*)d_in[2];
    const float* Kw[11];
    for (int i = 0; i < 11; i++) Kw[i] = (const float*)d_in[3 + i];
    float* out = (float*)d_out;
    float* ws = (float*)d_ws;

    const int Ns[4] = {4096, 2048, 1024, 512};

    size_t off = 0;
    auto alloc = [&](size_t n) { float* p = ws + off; off += (n + 63) & ~(size_t)63; return p; };
    float* L[4];
    L[0] = alloc(16777216); L[1] = alloc(4194304); L[2] = alloc(1048576); L[3] = alloc(262144);
    float* Xn = alloc(3 * 4096);
    float* sqv = alloc(4096);
    float* dsum = alloc(4096);
    float* stats = alloc(4);
    float* mlev[4];
    mlev[0] = const_cast<float*>(m0);
    mlev[1] = alloc(2048); mlev[2] = alloc(1024); mlev[3] = alloc(512);
    float* Xlev[4];
    Xlev[0] = const_cast<float*>(X0);
    Xlev[1] = alloc(3 * 2048); Xlev[2] = alloc(3 * 1024); Xlev[3] = alloc(3 * 512);
    float* pA[4], *pB[4], *xs[3];
    for (int l = 0; l < 4; l++) { pA[l] = alloc(131072); pB[l] = alloc(131072); }
    for (int l = 0; l < 3; l++) xs[l] = alloc(131072);
    float* zbig = alloc(262144);
    float* ybuf = alloc(262144);
    float* yp = alloc(1048576);

    auto build_lap = [&](int lvl) {
        int N = Ns[lvl];
        k_rowstats<<<3, 256, 0, stream>>>(Xlev[lvl], N, stats);
        k_xnsq<<<N / 256, 256, 0, stream>>>(Xlev[lvl], stats, Xn, sqv, N);
        k_we<<<dim3(N / 256, N), 256, 0, stream>>>(Xn, sqv, L[lvl], N);
        k_rowsum<<<N, 256, 0, stream>>>(L[lvl], dsum, N);
        k_finalize<<<(unsigned)(((size_t)N * N) / 256), 256, 0, stream>>>(L[lvl], dsum, mlev[lvl], N);
    };

    auto matmul = [&](const float* xv, int C, int lvl, float* yout) {
        int N = Ns[lvl];
        int jb = N / 128, cb = C / 32;
        int ks = 1;
        while (ks < 8 && jb * cb * ks < 256) ks <<= 1;
        k_matmul<<<dim3(jb, cb, ks), 256, 0, stream>>>(xv, L[lvl], yp, C, N, N / ks);
        size_t total = (size_t)C * N;
        k_reduce<<<(unsigned)(total / 256), 256, 0, stream>>>(yp, yout, ks, total);
    };

    auto conv = [&](const float* yv, const float* Kv, int lvl, const float* resv, float* ov,
                    int Cin, int Cout, int tr) {
        int N = Ns[lvl];
        if (N == 4096)      k_conv_in<16><<<Cout, 256, 0, stream>>>(yv, Kv, mlev[lvl], resv, ov, Cin, Cout, N, tr);
        else if (N == 2048) k_conv_in<8><<<Cout, 256, 0, stream>>>(yv, Kv, mlev[lvl], resv, ov, Cin, Cout, N, tr);
        else                k_conv_in<4><<<Cout, 256, 0, stream>>>(yv, Kv, mlev[lvl], resv, ov, Cin, Cout, N, tr);
    };

    // ---- down ----
    build_lap(0);
    matmul(x_in, 32, 0, ybuf);  conv(ybuf, Kw[0], 0, x_in, pA[0], 32, 32, 0);
    matmul(pA[0], 32, 0, ybuf); conv(ybuf, Kw[1], 0, pA[0], xs[0], 32, 32, 0);
    matmul(xs[0], 32, 0, ybuf); conv(ybuf, Kw[2], 0, nullptr, zbig, 32, 64, 0);
    k_pool<<<(64 * 2048) / 256, 256, 0, stream>>>(zbig, pA[1], 64, 4096);
    k_pool<<<(2048 + 255) / 256, 256, 0, stream>>>(mlev[0], mlev[1], 1, 4096);
    k_pool<<<(3 * 2048) / 256, 256, 0, stream>>>(Xlev[0], Xlev[1], 3, 4096);
    build_lap(1);
    matmul(pA[1], 64, 1, ybuf); conv(ybuf, Kw[3], 1, pA[1], pB[1], 64, 64, 0);
    matmul(pB[1], 64, 1, ybuf); conv(ybuf, Kw[4], 1, pB[1], xs[1], 64, 64, 0);
    matmul(xs[1], 64, 1, ybuf); conv(ybuf, Kw[5], 1, nullptr, zbig, 64, 128, 0);
    k_pool<<<(128 * 1024) / 256, 256, 0, stream>>>(zbig, pA[2], 128, 2048);
    k_pool<<<(1024 + 255) / 256, 256, 0, stream>>>(mlev[1], mlev[2], 1, 2048);
    k_pool<<<(3 * 1024 + 255) / 256, 256, 0, stream>>>(Xlev[1], Xlev[2], 3, 2048);
    build_lap(2);
    matmul(pA[2], 128, 2, ybuf); conv(ybuf, Kw[6], 2, pA[2], pB[2], 128, 128, 0);
    matmul(pB[2], 128, 2, ybuf); conv(ybuf, Kw[7], 2, pB[2], xs[2], 128, 128, 0);
    matmul(xs[2], 128, 2, ybuf); conv(ybuf, Kw[8], 2, nullptr, zbig, 128, 256, 0);
    k_pool<<<(256 * 512) / 256, 256, 0, stream>>>(zbig, pA[3], 256, 1024);
    k_pool<<<(512 + 255) / 256, 256, 0, stream>>>(mlev[2], mlev[3], 1, 1024);
    k_pool<<<(3 * 512 + 255) / 256, 256, 0, stream>>>(Xlev[2], Xlev[3], 3, 1024);
    build_lap(3);
    matmul(pA[3], 256, 3, ybuf); conv(ybuf, Kw[9], 3, pA[3], pB[3], 256, 256, 0);
    matmul(pB[3], 256, 3, ybuf); conv(ybuf, Kw[10], 3, pB[3], pA[3], 256, 256, 0);

    // ---- up ----
    matmul(pA[3], 256, 3, ybuf); conv(ybuf, Kw[10], 3, pA[3], pB[3], 256, 256, 1);
    matmul(pB[3], 256, 3, ybuf); conv(ybuf, Kw[9], 3, pB[3], pA[3], 256, 256, 1);

    k_repeat<<<(256 * 512) / 256, 256, 0, stream>>>(pA[3], zbig, 256, 512);   // -> 256x1024
    matmul(zbig, 256, 2, ybuf); conv(ybuf, Kw[8], 2, xs[2], pB[2], 256, 128, 1);
    matmul(pB[2], 128, 2, ybuf); conv(ybuf, Kw[7], 2, pB[2], pA[2], 128, 128, 1);
    matmul(pA[2], 128, 2, ybuf); conv(ybuf, Kw[6], 2, pA[2], pB[2], 128, 128, 1);

    k_repeat<<<(128 * 1024) / 256, 256, 0, stream>>>(pB[2], zbig, 128, 1024); // -> 128x2048
    matmul(zbig, 128, 1, ybuf); conv(ybuf, Kw[5], 1, xs[1], pA[1], 128, 64, 1);
    matmul(pA[1], 64, 1, ybuf); conv(ybuf, Kw[4], 1, pA[1], pB[1], 64, 64, 1);
    matmul(pB[1], 64, 1, ybuf); conv(ybuf, Kw[3], 1, pB[1], pA[1], 64, 64, 1);

    k_repeat<<<(64 * 2048) / 256, 256, 0, stream>>>(pA[1], zbig, 64, 2048);   // -> 64x4096
    matmul(zbig, 64, 0, ybuf); conv(ybuf, Kw[2], 0, xs[0], pB[0], 64, 32, 1);
    matmul(pB[0], 32, 0, ybuf); conv(ybuf, Kw[1], 0, pB[0], pA[0], 32, 32, 1);
    matmul(pA[0], 32, 0, ybuf); conv(ybuf, Kw[0], 0, pA[0], out, 32, 32, 1);
}

// Round 3
// 2923.394 us; speedup vs baseline: 1.6961x; 1.6961x over previous
//
#include <hip/hip_runtime.h>
#include <math.h>

// ---------- Laplacian pipeline ----------

// one block per row (3 rows); stats[r] = 1/(std_ddof1 + 0.01)
__global__ __launch_bounds__(256) void k_rowstats(const float* __restrict__ X, int N,
                                                  float* __restrict__ stats) {
    int r = blockIdx.x;
    const float* row = X + (size_t)r * N;
    double s = 0.0, ss = 0.0;
    for (int i = threadIdx.x; i < N; i += 256) { double v = row[i]; s += v; ss += v * v; }
    __shared__ double sh_s[256], sh_ss[256];
    sh_s[threadIdx.x] = s; sh_ss[threadIdx.x] = ss; __syncthreads();
    for (int off = 128; off > 0; off >>= 1) {
        if (threadIdx.x < off) { sh_s[threadIdx.x] += sh_s[threadIdx.x + off];
                                 sh_ss[threadIdx.x] += sh_ss[threadIdx.x + off]; }
        __syncthreads();
    }
    if (threadIdx.x == 0) {
        double mean = sh_s[0] / N;
        double var = (sh_ss[0] - mean * sh_s[0]) / (N - 1);
        if (var < 0.0) var = 0.0;
        stats[r] = 1.0f / ((float)sqrt(var) + 0.01f);
    }
}

// W[i,j] = exp(-max(sq_i+sq_j-2<xi,xj>,0)/10), Xn computed on the fly,
// plus per-block row partial sums -> part[i*NB + bj]
__global__ __launch_bounds__(256) void k_we(const float* __restrict__ X,
                                            const float* __restrict__ stats,
                                            float* __restrict__ W,
                                            float* __restrict__ part, int N) {
    int i = blockIdx.y, t = threadIdx.x;
    int NB = gridDim.x;
    int j = blockIdx.x * 1024 + t * 4;
    float s0 = stats[0], s1 = stats[1], s2 = stats[2];
    float a0 = X[i] * s0, a1 = X[N + i] * s1, a2 = X[2 * N + i] * s2;
    float si = a0 * a0 + a1 * a1 + a2 * a2;
    float psum = 0.f;
    if (j < N) {
        float4 x0 = *(const float4*)(X + j);
        float4 x1 = *(const float4*)(X + N + j);
        float4 x2 = *(const float4*)(X + 2 * N + j);
        float4 wv;
        float b0, b1, b2, sj, D;
        b0 = x0.x * s0; b1 = x1.x * s1; b2 = x2.x * s2; sj = b0*b0+b1*b1+b2*b2;
        D = fmaxf(si + sj - 2.f*(a0*b0 + a1*b1 + a2*b2), 0.f);
        wv.x = exp2f(-D * 0.14426950408889634f);
        b0 = x0.y * s0; b1 = x1.y * s1; b2 = x2.y * s2; sj = b0*b0+b1*b1+b2*b2;
        D = fmaxf(si + sj - 2.f*(a0*b0 + a1*b1 + a2*b2), 0.f);
        wv.y = exp2f(-D * 0.14426950408889634f);
        b0 = x0.z * s0; b1 = x1.z * s1; b2 = x2.z * s2; sj = b0*b0+b1*b1+b2*b2;
        D = fmaxf(si + sj - 2.f*(a0*b0 + a1*b1 + a2*b2), 0.f);
        wv.z = exp2f(-D * 0.14426950408889634f);
        b0 = x0.w * s0; b1 = x1.w * s1; b2 = x2.w * s2; sj = b0*b0+b1*b1+b2*b2;
        D = fmaxf(si + sj - 2.f*(a0*b0 + a1*b1 + a2*b2), 0.f);
        wv.w = exp2f(-D * 0.14426950408889634f);
        *(float4*)(W + (size_t)i * N + j) = wv;
        psum = wv.x + wv.y + wv.z + wv.w;
    }
    __shared__ float red[256];
    red[t] = psum; __syncthreads();
    for (int off = 128; off > 0; off >>= 1) {
        if (t < off) red[t] += red[t + off];
        __syncthreads();
    }
    if (t == 0) part[(size_t)i * NB + blockIdx.x] = red[0];
}

// L[i,j] = M_i*M_j*((i==j)?d_i:0 - W[i,j]) + (i==j)*(1-M_j), in place; d from partials
__global__ __launch_bounds__(256) void k_finalize(float* __restrict__ W,
                                                  const float* __restrict__ part,
                                                  const float* __restrict__ m, int N, int NB) {
    int i = blockIdx.y;
    int j = blockIdx.x * 1024 + threadIdx.x * 4;
    float d = 0.f;
    for (int k = 0; k < NB; k++) d += part[(size_t)i * NB + k];
    float mi = m[i];
    if (j < N) {
        float4 w = *(const float4*)(W + (size_t)i * N + j);
        float4 mj = *(const float4*)(m + j);
        float4 o;
        float lv;
        lv = ((j + 0 == i) ? d : 0.f) - w.x; lv = mi * mj.x * lv; if (j + 0 == i) lv += 1.f - mj.x; o.x = lv;
        lv = ((j + 1 == i) ? d : 0.f) - w.y; lv = mi * mj.y * lv; if (j + 1 == i) lv += 1.f - mj.y; o.y = lv;
        lv = ((j + 2 == i) ? d : 0.f) - w.z; lv = mi * mj.z * lv; if (j + 2 == i) lv += 1.f - mj.z; o.z = lv;
        lv = ((j + 3 == i) ? d : 0.f) - w.w; lv = mi * mj.w * lv; if (j + 3 == i) lv += 1.f - mj.w; o.w = lv;
        *(float4*)(W + (size_t)i * N + j) = o;
    }
}

// ---------- GEMM: y[c,j] = sum_i x[c,i] * L[i,j], split-K over grid.z ----------

__global__ __launch_bounds__(256) void k_matmul(const float* __restrict__ x,
                                                const float* __restrict__ L,
                                                float* __restrict__ yp, int C, int N, int chunk) {
    __shared__ float Ls[32][128];
    __shared__ float xsT[32][36];
    int t = threadIdx.x;
    int jl = t & 31;       // 32 col-quads -> 128 cols
    int cg = t >> 5;       // 8 channel groups of 4
    int j0 = blockIdx.x * 128;
    int c0 = blockIdx.y * 32;
    int i_begin = blockIdx.z * chunk;
    float acc[4][4];
    #pragma unroll
    for (int r = 0; r < 4; r++)
        #pragma unroll
        for (int c = 0; c < 4; c++) acc[r][c] = 0.f;

    for (int i0 = i_begin; i0 < i_begin + chunk; i0 += 32) {
        #pragma unroll
        for (int rr = 0; rr < 4; rr++) {
            int idx = rr * 256 + t;
            int row = idx >> 5;
            int col = (idx & 31) << 2;
            *(float4*)(&Ls[row][col]) = *(const float4*)(L + (size_t)(i0 + row) * N + j0 + col);
        }
        #pragma unroll
        for (int ll = 0; ll < 4; ll++) {
            int idx = ll * 256 + t;
            int cc = idx >> 5;
            int ii = idx & 31;
            xsT[ii][cc] = x[(size_t)(c0 + cc) * N + i0 + ii];
        }
        __syncthreads();
        #pragma unroll
        for (int ii = 0; ii < 32; ii++) {
            float4 a = *(const float4*)(&xsT[ii][cg * 4]);
            float4 lv = *(const float4*)(&Ls[ii][jl * 4]);
            acc[0][0] += a.x * lv.x; acc[0][1] += a.x * lv.y; acc[0][2] += a.x * lv.z; acc[0][3] += a.x * lv.w;
            acc[1][0] += a.y * lv.x; acc[1][1] += a.y * lv.y; acc[1][2] += a.y * lv.z; acc[1][3] += a.y * lv.w;
            acc[2][0] += a.z * lv.x; acc[2][1] += a.z * lv.y; acc[2][2] += a.z * lv.z; acc[2][3] += a.z * lv.w;
            acc[3][0] += a.w * lv.x; acc[3][1] += a.w * lv.y; acc[3][2] += a.w * lv.z; acc[3][3] += a.w * lv.w;
        }
        __syncthreads();
    }
    float* yo = yp + (size_t)blockIdx.z * C * N;
    #pragma unroll
    for (int r = 0; r < 4; r++) {
        int c = c0 + cg * 4 + r;
        *(float4*)(yo + (size_t)c * N + j0 + jl * 4) = make_float4(acc[r][0], acc[r][1], acc[r][2], acc[r][3]);
    }
}

__global__ __launch_bounds__(256) void k_reduce(const float* __restrict__ yp,
                                                float* __restrict__ y, int parts, size_t total) {
    size_t idx = (size_t)blockIdx.x * 256 + threadIdx.x;
    if (idx >= total) return;
    float s = 0.f;
    for (int p = 0; p < parts; p++) s += yp[(size_t)p * total + idx];
    y[idx] = s;
}

// ---------- conv phase A: 9-tap conv + mask, partial IN stats ----------
// grid (N/512, C_out); 2 cols/thread, window read straight from global.
__global__ __launch_bounds__(256) void k_convA(const float* __restrict__ y,
                                               const float* __restrict__ Kw,
                                               const float* __restrict__ m,
                                               float* __restrict__ zm,
                                               float2* __restrict__ sp,
                                               int C_in, int C_out, int N, int transpose) {
    int o = blockIdx.y;
    int t = threadIdx.x;
    int NB = gridDim.x;
    int base = blockIdx.x * 512 + t * 2;
    bool interior = (base >= 4) && (base + 6 <= N);
    float acc0 = 0.f, acc1 = 0.f;

    size_t wbase; int wstride;
    if (!transpose) { wbase = (size_t)o * C_in * 9; wstride = 9; }
    else            { wbase = (size_t)o * 9;        wstride = C_out * 9; }

    for (int i = 0; i < C_in; i++) {
        const float* yr = y + (size_t)i * N;
        float f[10];
        if (interior) {
            #pragma unroll
            for (int q = 0; q < 5; q++) {
                float2 v = *(const float2*)(yr + base - 4 + 2 * q);
                f[2 * q] = v.x; f[2 * q + 1] = v.y;
            }
        } else {
            #pragma unroll
            for (int q = 0; q < 5; q++) {
                int c = base - 4 + 2 * q;
                float2 v = (c >= 0 && c < N) ? *(const float2*)(yr + c) : make_float2(0.f, 0.f);
                f[2 * q] = v.x; f[2 * q + 1] = v.y;
            }
        }
        const float* wp = Kw + wbase + (size_t)i * wstride;
        float wt[9];
        if (!transpose) {
            #pragma unroll
            for (int tp = 0; tp < 9; tp++) wt[tp] = wp[tp];
        } else {
            #pragma unroll
            for (int tp = 0; tp < 9; tp++) wt[tp] = wp[8 - tp];
        }
        #pragma unroll
        for (int tp = 0; tp < 9; tp++) {
            acc0 += f[tp] * wt[tp];
            acc1 += f[tp + 1] * wt[tp];
        }
    }

    float2 mv = *(const float2*)(m + base);
    float z0 = acc0 * mv.x, z1 = acc1 * mv.y;
    *(float2*)(zm + (size_t)o * N + base) = make_float2(z0, z1);

    __shared__ float red[256], red2[256];
    red[t] = z0 + z1; red2[t] = z0 * z0 + z1 * z1;
    __syncthreads();
    for (int off = 128; off > 0; off >>= 1) {
        if (t < off) { red[t] += red[t + off]; red2[t] += red2[t + off]; }
        __syncthreads();
    }
    if (t == 0) sp[(size_t)o * NB + blockIdx.x] = make_float2(red[0], red2[0]);
}

// ---------- conv phase C: instance-norm apply + relu + residual ----------
__global__ __launch_bounds__(256) void k_convC(const float* __restrict__ zm,
                                               const float2* __restrict__ sp,
                                               const float* __restrict__ res,
                                               float* __restrict__ xout, int N, int NB) {
    int o = blockIdx.y;
    int t = threadIdx.x;
    int base = blockIdx.x * 512 + t * 2;
    float s = 0.f, ss = 0.f;
    for (int k = 0; k < NB; k++) { float2 p = sp[(size_t)o * NB + k]; s += p.x; ss += p.y; }
    float mean = s / N;
    float var = fmaxf(ss / N - mean * mean, 0.f);
    float rs = rsqrtf(var + 1e-5f);
    float2 z = *(const float2*)(zm + (size_t)o * N + base);
    float v0 = fmaxf((z.x - mean) * rs, 0.f);
    float v1 = fmaxf((z.y - mean) * rs, 0.f);
    if (res) {
        float2 r = *(const float2*)(res + (size_t)o * N + base);
        v0 += r.x; v1 += r.y;
    }
    *(float2*)(xout + (size_t)o * N + base) = make_float2(v0, v1);
}

// ---------- fused pool (z rows + mask + X) ----------
__global__ __launch_bounds__(256) void k_poolall(const float* __restrict__ z_in, float* __restrict__ z_out, int Cz,
                                                 const float* __restrict__ m_in, float* __restrict__ m_out,
                                                 const float* __restrict__ X_in, float* __restrict__ X_out, int Nin) {
    int No = Nin >> 1;
    int idx = blockIdx.x * 256 + threadIdx.x;
    int total = (Cz + 4) * No;
    if (idx >= total) return;
    int r = idx / No, ii = idx - r * No;
    const float* src; float* dst;
    if (r < Cz)      { src = z_in + (size_t)r * Nin; dst = z_out + (size_t)r * No; }
    else if (r == Cz){ src = m_in; dst = m_out; }
    else             { src = X_in + (size_t)(r - Cz - 1) * Nin; dst = X_out + (size_t)(r - Cz - 1) * No; }
    float a = (ii > 0) ? src[2 * ii - 1] : 0.f;
    dst[ii] = (a + src[2 * ii] + src[2 * ii + 1]) * (1.f / 3.f);
}

__global__ __launch_bounds__(256) void k_repeat(const float* __restrict__ in,
                                                float* __restrict__ out, int rows, int Nin) {
    int idx = blockIdx.x * 256 + threadIdx.x;
    if (idx >= rows * Nin) return;
    int r = idx / Nin, i = idx - r * Nin;
    float v = in[(size_t)r * Nin + i];
    out[(size_t)r * 2 * Nin + 2 * i] = v;
    out[(size_t)r * 2 * Nin + 2 * i + 1] = v;
}

// ---------- host ----------

extern "C" void kernel_launch(void* const* d_in, const int* in_sizes, int n_in,
                              void* d_out, int out_size, void* d_ws, size_t ws_size,
                              hipStream_t stream) {
    (void)in_sizes; (void)n_in; (void)out_size; (void)ws_size;
    const float* x_in = (const float*)d_in[0];
    const float* X0 = (const float*)d_in[1];
    const float* m0 = (const float*)d_in[2];
    const float* Kw[11];
    for (int i = 0; i < 11; i++) Kw[i] = (const float*)d_in[3 + i];
    float* out = (float*)d_out;
    float* ws = (float*)d_ws;

    const int Ns[4] = {4096, 2048, 1024, 512};

    size_t off = 0;
    auto alloc = [&](size_t n) { float* p = ws + off; off += (n + 63) & ~(size_t)63; return p; };
    float* L[4];
    L[0] = alloc(16777216); L[1] = alloc(4194304); L[2] = alloc(1048576); L[3] = alloc(262144);
    float* part = alloc(16384);
    float* stats = alloc(4);
    float* spbuf = alloc(1024);   // float2[512]
    float* zmbuf = alloc(262144);
    float* mlev[4];
    mlev[0] = const_cast<float*>(m0);
    mlev[1] = alloc(2048); mlev[2] = alloc(1024); mlev[3] = alloc(512);
    float* Xlev[4];
    Xlev[0] = const_cast<float*>(X0);
    Xlev[1] = alloc(3 * 2048); Xlev[2] = alloc(3 * 1024); Xlev[3] = alloc(3 * 512);
    float* pA[4], *pB[4], *xs[3];
    for (int l = 0; l < 4; l++) { pA[l] = alloc(131072); pB[l] = alloc(131072); }
    for (int l = 0; l < 3; l++) xs[l] = alloc(131072);
    float* zbig = alloc(262144);
    float* ybuf = alloc(262144);
    float* yp = alloc(1048576);

    auto build_lap = [&](int lvl) {
        int N = Ns[lvl];
        int NB = (N + 1023) / 1024;
        k_rowstats<<<3, 256, 0, stream>>>(Xlev[lvl], N, stats);
        k_we<<<dim3(NB, N), 256, 0, stream>>>(Xlev[lvl], stats, L[lvl], part, N);
        k_finalize<<<dim3(NB, N), 256, 0, stream>>>(L[lvl], part, mlev[lvl], N, NB);
    };

    auto matmul = [&](const float* xv, int C, int lvl, float* yout) {
        int N = Ns[lvl];
        int jb = N / 128, cb = C / 32;
        int ks = 1;
        while (ks < 8 && jb * cb * ks < 256) ks <<= 1;
        k_matmul<<<dim3(jb, cb, ks), 256, 0, stream>>>(xv, L[lvl], yp, C, N, N / ks);
        size_t total = (size_t)C * N;
        k_reduce<<<(unsigned)((total + 255) / 256), 256, 0, stream>>>(yp, yout, ks, total);
    };

    auto conv = [&](const float* yv, const float* Kv, int lvl, const float* resv, float* ov,
                    int Cin, int Cout, int tr) {
        int N = Ns[lvl];
        int NBc = (N + 511) / 512;
        k_convA<<<dim3(NBc, Cout), 256, 0, stream>>>(yv, Kv, mlev[lvl], zmbuf, (float2*)spbuf, Cin, Cout, N, tr);
        k_convC<<<dim3(NBc, Cout), 256, 0, stream>>>(zmbuf, (const float2*)spbuf, resv, ov, N, NBc);
    };

    auto poolall = [&](const float* z_in, float* z_out, int Cz, int lvl_from) {
        int Nin = Ns[lvl_from];
        int No = Nin >> 1;
        int total = (Cz + 4) * No;
        k_poolall<<<(total + 255) / 256, 256, 0, stream>>>(z_in, z_out, Cz,
                                                           mlev[lvl_from], mlev[lvl_from + 1],
                                                           Xlev[lvl_from], Xlev[lvl_from + 1], Nin);
    };

    // ---- down ----
    build_lap(0);
    matmul(x_in, 32, 0, ybuf);  conv(ybuf, Kw[0], 0, x_in, pA[0], 32, 32, 0);
    matmul(pA[0], 32, 0, ybuf); conv(ybuf, Kw[1], 0, pA[0], xs[0], 32, 32, 0);
    matmul(xs[0], 32, 0, ybuf); conv(ybuf, Kw[2], 0, nullptr, zbig, 32, 64, 0);
    poolall(zbig, pA[1], 64, 0);
    build_lap(1);
    matmul(pA[1], 64, 1, ybuf); conv(ybuf, Kw[3], 1, pA[1], pB[1], 64, 64, 0);
    matmul(pB[1], 64, 1, ybuf); conv(ybuf, Kw[4], 1, pB[1], xs[1], 64, 64, 0);
    matmul(xs[1], 64, 1, ybuf); conv(ybuf, Kw[5], 1, nullptr, zbig, 64, 128, 0);
    poolall(zbig, pA[2], 128, 1);
    build_lap(2);
    matmul(pA[2], 128, 2, ybuf); conv(ybuf, Kw[6], 2, pA[2], pB[2], 128, 128, 0);
    matmul(pB[2], 128, 2, ybuf); conv(ybuf, Kw[7], 2, pB[2], xs[2], 128, 128, 0);
    matmul(xs[2], 128, 2, ybuf); conv(ybuf, Kw[8], 2, nullptr, zbig, 128, 256, 0);
    poolall(zbig, pA[3], 256, 2);
    build_lap(3);
    matmul(pA[3], 256, 3, ybuf); conv(ybuf, Kw[9], 3, pA[3], pB[3], 256, 256, 0);
    matmul(pB[3], 256, 3, ybuf); conv(ybuf, Kw[10], 3, pB[3], pA[3], 256, 256, 0);

    // ---- up ----
    matmul(pA[3], 256, 3, ybuf); conv(ybuf, Kw[10], 3, pA[3], pB[3], 256, 256, 1);
    matmul(pB[3], 256, 3, ybuf); conv(ybuf, Kw[9], 3, pB[3], pA[3], 256, 256, 1);

    k_repeat<<<(256 * 512) / 256, 256, 0, stream>>>(pA[3], zbig, 256, 512);   // -> 256x1024
    matmul(zbig, 256, 2, ybuf); conv(ybuf, Kw[8], 2, xs[2], pB[2], 256, 128, 1);
    matmul(pB[2], 128, 2, ybuf); conv(ybuf, Kw[7], 2, pB[2], pA[2], 128, 128, 1);
    matmul(pA[2], 128, 2, ybuf); conv(ybuf, Kw[6], 2, pA[2], pB[2], 128, 128, 1);

    k_repeat<<<(128 * 1024) / 256, 256, 0, stream>>>(pB[2], zbig, 128, 1024); // -> 128x2048
    matmul(zbig, 128, 1, ybuf); conv(ybuf, Kw[5], 1, xs[1], pA[1], 128, 64, 1);
    matmul(pA[1], 64, 1, ybuf); conv(ybuf, Kw[4], 1, pA[1], pB[1], 64, 64, 1);
    matmul(pB[1], 64, 1, ybuf); conv(ybuf, Kw[3], 1, pB[1], pA[1], 64, 64, 1);

    k_repeat<<<(64 * 2048) / 256, 256, 0, stream>>>(pA[1], zbig, 64, 2048);   // -> 64x4096
    matmul(zbig, 64, 0, ybuf); conv(ybuf, Kw[2], 0, xs[0], pB[0], 64, 32, 1);
    matmul(pB[0], 32, 0, ybuf); conv(ybuf, Kw[1], 0, pB[0], pA[0], 32, 32, 1);
    matmul(pA[0], 32, 0, ybuf); conv(ybuf, Kw[0], 0, pA[0], out, 32, 32, 1);
}

// Round 5
// 1478.293 us; speedup vs baseline: 3.3541x; 1.9775x over previous
//
#include <hip/hip_runtime.h>
#include <math.h>

// ---------- Laplacian pipeline ----------

// one block per row (3 rows); stats[r] = 1/(std_ddof1 + 0.01)
__global__ __launch_bounds__(256) void k_rowstats(const float* __restrict__ X, int N,
                                                  float* __restrict__ stats) {
    int r = blockIdx.x;
    const float* row = X + (size_t)r * N;
    double s = 0.0, ss = 0.0;
    for (int i = threadIdx.x; i < N; i += 256) { double v = row[i]; s += v; ss += v * v; }
    __shared__ double sh_s[256], sh_ss[256];
    sh_s[threadIdx.x] = s; sh_ss[threadIdx.x] = ss; __syncthreads();
    for (int off = 128; off > 0; off >>= 1) {
        if (threadIdx.x < off) { sh_s[threadIdx.x] += sh_s[threadIdx.x + off];
                                 sh_ss[threadIdx.x] += sh_ss[threadIdx.x + off]; }
        __syncthreads();
    }
    if (threadIdx.x == 0) {
        double mean = sh_s[0] / N;
        double var = (sh_ss[0] - mean * sh_s[0]) / (N - 1);
        if (var < 0.0) var = 0.0;
        stats[r] = 1.0f / ((float)sqrt(var) + 0.01f);
    }
}

// W[i,j] = exp(-max(sq_i+sq_j-2<xi,xj>,0)/10), Xn computed on the fly,
// plus per-block row partial sums -> part[i*NB + bj]
__global__ __launch_bounds__(256) void k_we(const float* __restrict__ X,
                                            const float* __restrict__ stats,
                                            float* __restrict__ W,
                                            float* __restrict__ part, int N) {
    int i = blockIdx.y, t = threadIdx.x;
    int NB = gridDim.x;
    int j = blockIdx.x * 1024 + t * 4;
    float s0 = stats[0], s1 = stats[1], s2 = stats[2];
    float a0 = X[i] * s0, a1 = X[N + i] * s1, a2 = X[2 * N + i] * s2;
    float si = a0 * a0 + a1 * a1 + a2 * a2;
    float psum = 0.f;
    if (j < N) {
        float4 x0 = *(const float4*)(X + j);
        float4 x1 = *(const float4*)(X + N + j);
        float4 x2 = *(const float4*)(X + 2 * N + j);
        float4 wv;
        float b0, b1, b2, sj, D;
        b0 = x0.x * s0; b1 = x1.x * s1; b2 = x2.x * s2; sj = b0*b0+b1*b1+b2*b2;
        D = fmaxf(si + sj - 2.f*(a0*b0 + a1*b1 + a2*b2), 0.f);
        wv.x = exp2f(-D * 0.14426950408889634f);
        b0 = x0.y * s0; b1 = x1.y * s1; b2 = x2.y * s2; sj = b0*b0+b1*b1+b2*b2;
        D = fmaxf(si + sj - 2.f*(a0*b0 + a1*b1 + a2*b2), 0.f);
        wv.y = exp2f(-D * 0.14426950408889634f);
        b0 = x0.z * s0; b1 = x1.z * s1; b2 = x2.z * s2; sj = b0*b0+b1*b1+b2*b2;
        D = fmaxf(si + sj - 2.f*(a0*b0 + a1*b1 + a2*b2), 0.f);
        wv.z = exp2f(-D * 0.14426950408889634f);
        b0 = x0.w * s0; b1 = x1.w * s1; b2 = x2.w * s2; sj = b0*b0+b1*b1+b2*b2;
        D = fmaxf(si + sj - 2.f*(a0*b0 + a1*b1 + a2*b2), 0.f);
        wv.w = exp2f(-D * 0.14426950408889634f);
        *(float4*)(W + (size_t)i * N + j) = wv;
        psum = wv.x + wv.y + wv.z + wv.w;
    }
    __shared__ float red[256];
    red[t] = psum; __syncthreads();
    for (int off = 128; off > 0; off >>= 1) {
        if (t < off) red[t] += red[t + off];
        __syncthreads();
    }
    if (t == 0) part[(size_t)i * NB + blockIdx.x] = red[0];
}

// L[i,j] = M_i*M_j*((i==j)?d_i:0 - W[i,j]) + (i==j)*(1-M_j), in place; d from partials
__global__ __launch_bounds__(256) void k_finalize(float* __restrict__ W,
                                                  const float* __restrict__ part,
                                                  const float* __restrict__ m, int N, int NB) {
    int i = blockIdx.y;
    int j = blockIdx.x * 1024 + threadIdx.x * 4;
    float d = 0.f;
    for (int k = 0; k < NB; k++) d += part[(size_t)i * NB + k];
    float mi = m[i];
    if (j < N) {
        float4 w = *(const float4*)(W + (size_t)i * N + j);
        float4 mj = *(const float4*)(m + j);
        float4 o;
        float lv;
        lv = ((j + 0 == i) ? d : 0.f) - w.x; lv = mi * mj.x * lv; if (j + 0 == i) lv += 1.f - mj.x; o.x = lv;
        lv = ((j + 1 == i) ? d : 0.f) - w.y; lv = mi * mj.y * lv; if (j + 1 == i) lv += 1.f - mj.y; o.y = lv;
        lv = ((j + 2 == i) ? d : 0.f) - w.z; lv = mi * mj.z * lv; if (j + 2 == i) lv += 1.f - mj.z; o.z = lv;
        lv = ((j + 3 == i) ? d : 0.f) - w.w; lv = mi * mj.w * lv; if (j + 3 == i) lv += 1.f - mj.w; o.w = lv;
        *(float4*)(W + (size_t)i * N + j) = o;
    }
}

// ---------- GEMM: y[c,j] = sum_i x[c,i] * L[i,j], split-K over grid.z ----------

__global__ __launch_bounds__(256) void k_matmul(const float* __restrict__ x,
                                                const float* __restrict__ L,
                                                float* __restrict__ yp, int C, int N, int chunk) {
    __shared__ float Ls[32][128];
    __shared__ float xsT[32][36];
    int t = threadIdx.x;
    int jl = t & 31;       // 32 col-quads -> 128 cols
    int cg = t >> 5;       // 8 channel groups of 4
    int j0 = blockIdx.x * 128;
    int c0 = blockIdx.y * 32;
    int i_begin = blockIdx.z * chunk;
    float acc[4][4];
    #pragma unroll
    for (int r = 0; r < 4; r++)
        #pragma unroll
        for (int c = 0; c < 4; c++) acc[r][c] = 0.f;

    for (int i0 = i_begin; i0 < i_begin + chunk; i0 += 32) {
        #pragma unroll
        for (int rr = 0; rr < 4; rr++) {
            int idx = rr * 256 + t;
            int row = idx >> 5;
            int col = (idx & 31) << 2;
            *(float4*)(&Ls[row][col]) = *(const float4*)(L + (size_t)(i0 + row) * N + j0 + col);
        }
        #pragma unroll
        for (int ll = 0; ll < 4; ll++) {
            int idx = ll * 256 + t;
            int cc = idx >> 5;
            int ii = idx & 31;
            xsT[ii][cc] = x[(size_t)(c0 + cc) * N + i0 + ii];
        }
        __syncthreads();
        #pragma unroll
        for (int ii = 0; ii < 32; ii++) {
            float4 a = *(const float4*)(&xsT[ii][cg * 4]);
            float4 lv = *(const float4*)(&Ls[ii][jl * 4]);
            acc[0][0] += a.x * lv.x; acc[0][1] += a.x * lv.y; acc[0][2] += a.x * lv.z; acc[0][3] += a.x * lv.w;
            acc[1][0] += a.y * lv.x; acc[1][1] += a.y * lv.y; acc[1][2] += a.y * lv.z; acc[1][3] += a.y * lv.w;
            acc[2][0] += a.z * lv.x; acc[2][1] += a.z * lv.y; acc[2][2] += a.z * lv.z; acc[2][3] += a.z * lv.w;
            acc[3][0] += a.w * lv.x; acc[3][1] += a.w * lv.y; acc[3][2] += a.w * lv.z; acc[3][3] += a.w * lv.w;
        }
        __syncthreads();
    }
    float* yo = yp + (size_t)blockIdx.z * C * N;
    #pragma unroll
    for (int r = 0; r < 4; r++) {
        int c = c0 + cg * 4 + r;
        *(float4*)(yo + (size_t)c * N + j0 + jl * 4) = make_float4(acc[r][0], acc[r][1], acc[r][2], acc[r][3]);
    }
}

__global__ __launch_bounds__(256) void k_reduce(const float* __restrict__ yp,
                                                float* __restrict__ y, int parts, size_t total) {
    size_t idx = (size_t)blockIdx.x * 256 + threadIdx.x;
    if (idx >= total) return;
    float s = 0.f;
    for (int p = 0; p < parts; p++) s += yp[(size_t)p * total + idx];
    y[idx] = s;
}

// ---------- conv phase A: partial 9-tap conv over a 32-channel chunk ----------
// grid (NBc, C_out, KS=C_in/32); weights for the chunk staged in LDS.
__global__ __launch_bounds__(256) void k_convA2(const float* __restrict__ y,
                                                const float* __restrict__ Kw,
                                                float* __restrict__ zp,
                                                int C_in, int C_out, int N, int transpose) {
    __shared__ float wsm[32][9];
    int o = blockIdx.y;
    int t = threadIdx.x;
    int ic0 = blockIdx.z * 32;

    // stage 32x9 weights (transpose/reversal handled here); 288 entries, 256 threads
    for (int idx = t; idx < 288; idx += 256) {
        int ii = idx / 9, tap = idx - ii * 9;
        float wv;
        if (!transpose) wv = Kw[((size_t)o * C_in + ic0 + ii) * 9 + tap];
        else            wv = Kw[((size_t)(ic0 + ii) * C_out + o) * 9 + (8 - tap)];
        wsm[ii][tap] = wv;
    }
    __syncthreads();

    int base = blockIdx.x * 512 + t * 2;
    bool interior = (base >= 4) && (base + 6 <= N);
    float acc0 = 0.f, acc1 = 0.f;

    for (int ii = 0; ii < 32; ii++) {
        const float* yr = y + (size_t)(ic0 + ii) * N;
        float f[10];
        if (interior) {
            #pragma unroll
            for (int q = 0; q < 5; q++) {
                float2 v = *(const float2*)(yr + base - 4 + 2 * q);
                f[2 * q] = v.x; f[2 * q + 1] = v.y;
            }
        } else {
            #pragma unroll
            for (int q = 0; q < 5; q++) {
                int c = base - 4 + 2 * q;
                float2 v = (c >= 0 && c < N) ? *(const float2*)(yr + c) : make_float2(0.f, 0.f);
                f[2 * q] = v.x; f[2 * q + 1] = v.y;
            }
        }
        #pragma unroll
        for (int tp = 0; tp < 9; tp++) {
            float wt = wsm[ii][tp];
            acc0 += f[tp] * wt;
            acc1 += f[tp + 1] * wt;
        }
    }
    *(float2*)(zp + ((size_t)blockIdx.z * C_out + o) * N + base) = make_float2(acc0, acc1);
}

// ---------- conv phase B: merge partials + mask + block IN stats ----------
__global__ __launch_bounds__(256) void k_convB(const float* __restrict__ zp,
                                               const float* __restrict__ m,
                                               float* __restrict__ zm,
                                               float2* __restrict__ sp,
                                               int C_out, int N, int KS) {
    int o = blockIdx.y;
    int t = threadIdx.x;
    int NB = gridDim.x;
    int base = blockIdx.x * 512 + t * 2;
    float z0 = 0.f, z1 = 0.f;
    for (int p = 0; p < KS; p++) {
        float2 v = *(const float2*)(zp + ((size_t)p * C_out + o) * N + base);
        z0 += v.x; z1 += v.y;
    }
    float2 mv = *(const float2*)(m + base);
    z0 *= mv.x; z1 *= mv.y;
    *(float2*)(zm + (size_t)o * N + base) = make_float2(z0, z1);

    __shared__ float red[256], red2[256];
    red[t] = z0 + z1; red2[t] = z0 * z0 + z1 * z1;
    __syncthreads();
    for (int off = 128; off > 0; off >>= 1) {
        if (t < off) { red[t] += red[t + off]; red2[t] += red2[t + off]; }
        __syncthreads();
    }
    if (t == 0) sp[(size_t)o * NB + blockIdx.x] = make_float2(red[0], red2[0]);
}

// ---------- conv phase C: instance-norm apply + relu + residual ----------
__global__ __launch_bounds__(256) void k_convC(const float* __restrict__ zm,
                                               const float2* __restrict__ sp,
                                               const float* __restrict__ res,
                                               float* __restrict__ xout, int N, int NB) {
    int o = blockIdx.y;
    int t = threadIdx.x;
    int base = blockIdx.x * 512 + t * 2;
    float s = 0.f, ss = 0.f;
    for (int k = 0; k < NB; k++) { float2 p = sp[(size_t)o * NB + k]; s += p.x; ss += p.y; }
    float mean = s / N;
    float var = fmaxf(ss / N - mean * mean, 0.f);
    float rs = rsqrtf(var + 1e-5f);
    float2 z = *(const float2*)(zm + (size_t)o * N + base);
    float v0 = fmaxf((z.x - mean) * rs, 0.f);
    float v1 = fmaxf((z.y - mean) * rs, 0.f);
    if (res) {
        float2 r = *(const float2*)(res + (size_t)o * N + base);
        v0 += r.x; v1 += r.y;
    }
    *(float2*)(xout + (size_t)o * N + base) = make_float2(v0, v1);
}

// ---------- fused pool (z rows + mask + X) ----------
__global__ __launch_bounds__(256) void k_poolall(const float* __restrict__ z_in, float* __restrict__ z_out, int Cz,
                                                 const float* __restrict__ m_in, float* __restrict__ m_out,
                                                 const float* __restrict__ X_in, float* __restrict__ X_out, int Nin) {
    int No = Nin >> 1;
    int idx = blockIdx.x * 256 + threadIdx.x;
    int total = (Cz + 4) * No;
    if (idx >= total) return;
    int r = idx / No, ii = idx - r * No;
    const float* src; float* dst;
    if (r < Cz)      { src = z_in + (size_t)r * Nin; dst = z_out + (size_t)r * No; }
    else if (r == Cz){ src = m_in; dst = m_out; }
    else             { src = X_in + (size_t)(r - Cz - 1) * Nin; dst = X_out + (size_t)(r - Cz - 1) * No; }
    float a = (ii > 0) ? src[2 * ii - 1] : 0.f;
    dst[ii] = (a + src[2 * ii] + src[2 * ii + 1]) * (1.f / 3.f);
}

__global__ __launch_bounds__(256) void k_repeat(const float* __restrict__ in,
                                                float* __restrict__ out, int rows, int Nin) {
    int idx = blockIdx.x * 256 + threadIdx.x;
    if (idx >= rows * Nin) return;
    int r = idx / Nin, i = idx - r * Nin;
    float v = in[(size_t)r * Nin + i];
    out[(size_t)r * 2 * Nin + 2 * i] = v;
    out[(size_t)r * 2 * Nin + 2 * i + 1] = v;
}

// ---------- host ----------

extern "C" void kernel_launch(void* const* d_in, const int* in_sizes, int n_in,
                              void* d_out, int out_size, void* d_ws, size_t ws_size,
                              hipStream_t stream) {
    (void)in_sizes; (void)n_in; (void)out_size; (void)ws_size;
    const float* x_in = (const float*)d_in[0];
    const float* X0 = (const float*)d_in[1];
    const float* m0 = (const float*)d_in[2];
    const float* Kw[11];
    for (int i = 0; i < 11; i++) Kw[i] = (const float*)d_in[3 + i];
    float* out = (float*)d_out;
    float* ws = (float*)d_ws;

    const int Ns[4] = {4096, 2048, 1024, 512};

    size_t off = 0;
    auto alloc = [&](size_t n) { float* p = ws + off; off += (n + 63) & ~(size_t)63; return p; };
    float* L[4];
    L[0] = alloc(16777216); L[1] = alloc(4194304); L[2] = alloc(1048576); L[3] = alloc(262144);
    float* part = alloc(16384);
    float* stats = alloc(4);
    float* spbuf = alloc(1024);   // float2[512]
    float* zmbuf = alloc(262144);
    float* mlev[4];
    mlev[0] = const_cast<float*>(m0);
    mlev[1] = alloc(2048); mlev[2] = alloc(1024); mlev[3] = alloc(512);
    float* Xlev[4];
    Xlev[0] = const_cast<float*>(X0);
    Xlev[1] = alloc(3 * 2048); Xlev[2] = alloc(3 * 1024); Xlev[3] = alloc(3 * 512);
    float* pA[4], *pB[4], *xs[3];
    for (int l = 0; l < 4; l++) { pA[l] = alloc(131072); pB[l] = alloc(131072); }
    for (int l = 0; l < 3; l++) xs[l] = alloc(131072);
    float* zbig = alloc(262144);
    float* ybuf = alloc(262144);
    float* yp = alloc(1048576);   // shared: matmul split-K partials AND conv split-C partials

    auto build_lap = [&](int lvl) {
        int N = Ns[lvl];
        int NB = (N + 1023) / 1024;
        k_rowstats<<<3, 256, 0, stream>>>(Xlev[lvl], N, stats);
        k_we<<<dim3(NB, N), 256, 0, stream>>>(Xlev[lvl], stats, L[lvl], part, N);
        k_finalize<<<dim3(NB, N), 256, 0, stream>>>(L[lvl], part, mlev[lvl], N, NB);
    };

    auto matmul = [&](const float* xv, int C, int lvl, float* yout) {
        int N = Ns[lvl];
        int jb = N / 128, cb = C / 32;
        int ks = 1;
        while (ks < 8 && jb * cb * ks < 256) ks <<= 1;
        k_matmul<<<dim3(jb, cb, ks), 256, 0, stream>>>(xv, L[lvl], yp, C, N, N / ks);
        size_t total = (size_t)C * N;
        k_reduce<<<(unsigned)((total + 255) / 256), 256, 0, stream>>>(yp, yout, ks, total);
    };

    auto conv = [&](const float* yv, const float* Kv, int lvl, const float* resv, float* ov,
                    int Cin, int Cout, int tr) {
        int N = Ns[lvl];
        int NBc = N / 512;
        int KS = Cin / 32;
        k_convA2<<<dim3(NBc, Cout, KS), 256, 0, stream>>>(yv, Kv, yp, Cin, Cout, N, tr);
        k_convB<<<dim3(NBc, Cout), 256, 0, stream>>>(yp, mlev[lvl], zmbuf, (float2*)spbuf, Cout, N, KS);
        k_convC<<<dim3(NBc, Cout), 256, 0, stream>>>(zmbuf, (const float2*)spbuf, resv, ov, N, NBc);
    };

    auto poolall = [&](const float* z_in, float* z_out, int Cz, int lvl_from) {
        int Nin = Ns[lvl_from];
        int No = Nin >> 1;
        int total = (Cz + 4) * No;
        k_poolall<<<(total + 255) / 256, 256, 0, stream>>>(z_in, z_out, Cz,
                                                           mlev[lvl_from], mlev[lvl_from + 1],
                                                           Xlev[lvl_from], Xlev[lvl_from + 1], Nin);
    };

    // ---- down ----
    build_lap(0);
    matmul(x_in, 32, 0, ybuf);  conv(ybuf, Kw[0], 0, x_in, pA[0], 32, 32, 0);
    matmul(pA[0], 32, 0, ybuf); conv(ybuf, Kw[1], 0, pA[0], xs[0], 32, 32, 0);
    matmul(xs[0], 32, 0, ybuf); conv(ybuf, Kw[2], 0, nullptr, zbig, 32, 64, 0);
    poolall(zbig, pA[1], 64, 0);
    build_lap(1);
    matmul(pA[1], 64, 1, ybuf); conv(ybuf, Kw[3], 1, pA[1], pB[1], 64, 64, 0);
    matmul(pB[1], 64, 1, ybuf); conv(ybuf, Kw[4], 1, pB[1], xs[1], 64, 64, 0);
    matmul(xs[1], 64, 1, ybuf); conv(ybuf, Kw[5], 1, nullptr, zbig, 64, 128, 0);
    poolall(zbig, pA[2], 128, 1);
    build_lap(2);
    matmul(pA[2], 128, 2, ybuf); conv(ybuf, Kw[6], 2, pA[2], pB[2], 128, 128, 0);
    matmul(pB[2], 128, 2, ybuf); conv(ybuf, Kw[7], 2, pB[2], xs[2], 128, 128, 0);
    matmul(xs[2], 128, 2, ybuf); conv(ybuf, Kw[8], 2, nullptr, zbig, 128, 256, 0);
    poolall(zbig, pA[3], 256, 2);
    build_lap(3);
    matmul(pA[3], 256, 3, ybuf); conv(ybuf, Kw[9], 3, pA[3], pB[3], 256, 256, 0);
    matmul(pB[3], 256, 3, ybuf); conv(ybuf, Kw[10], 3, pB[3], pA[3], 256, 256, 0);

    // ---- up ----
    matmul(pA[3], 256, 3, ybuf); conv(ybuf, Kw[10], 3, pA[3], pB[3], 256, 256, 1);
    matmul(pB[3], 256, 3, ybuf); conv(ybuf, Kw[9], 3, pB[3], pA[3], 256, 256, 1);

    k_repeat<<<(256 * 512) / 256, 256, 0, stream>>>(pA[3], zbig, 256, 512);   // -> 256x1024
    matmul(zbig, 256, 2, ybuf); conv(ybuf, Kw[8], 2, xs[2], pB[2], 256, 128, 1);
    matmul(pB[2], 128, 2, ybuf); conv(ybuf, Kw[7], 2, pB[2], pA[2], 128, 128, 1);
    matmul(pA[2], 128, 2, ybuf); conv(ybuf, Kw[6], 2, pA[2], pB[2], 128, 128, 1);

    k_repeat<<<(128 * 1024) / 256, 256, 0, stream>>>(pB[2], zbig, 128, 1024); // -> 128x2048
    matmul(zbig, 128, 1, ybuf); conv(ybuf, Kw[5], 1, xs[1], pA[1], 128, 64, 1);
    matmul(pA[1], 64, 1, ybuf); conv(ybuf, Kw[4], 1, pA[1], pB[1], 64, 64, 1);
    matmul(pB[1], 64, 1, ybuf); conv(ybuf, Kw[3], 1, pB[1], pA[1], 64, 64, 1);

    k_repeat<<<(64 * 2048) / 256, 256, 0, stream>>>(pA[1], zbig, 64, 2048);   // -> 64x4096
    matmul(zbig, 64, 0, ybuf); conv(ybuf, Kw[2], 0, xs[0], pB[0], 64, 32, 1);
    matmul(pB[0], 32, 0, ybuf); conv(ybuf, Kw[1], 0, pB[0], pA[0], 32, 32, 1);
    matmul(pA[0], 32, 0, ybuf); conv(ybuf, Kw[0], 0, pA[0], out, 32, 32, 1);
}

// Round 6
// 1242.379 us; speedup vs baseline: 3.9910x; 1.1899x over previous
//
#include <hip/hip_runtime.h>
#include <math.h>

typedef __attribute__((ext_vector_type(8))) short bf16x8;
typedef __attribute__((ext_vector_type(4))) float f32x4;

__device__ __forceinline__ ushort f2b(float f) {
    union { float f; unsigned u; } v; v.f = f;
    unsigned r = (v.u + 0x7FFFu + ((v.u >> 16) & 1u)) >> 16;
    return (ushort)r;
}
__device__ __forceinline__ float b2f(ushort h) {
    union { unsigned u; float f; } v; v.u = ((unsigned)h) << 16;
    return v.f;
}

// ---------- Laplacian pipeline ----------

__global__ __launch_bounds__(256) void k_rowstats(const float* __restrict__ X, int N,
                                                  float* __restrict__ stats) {
    int r = blockIdx.x;
    const float* row = X + (size_t)r * N;
    double s = 0.0, ss = 0.0;
    for (int i = threadIdx.x; i < N; i += 256) { double v = row[i]; s += v; ss += v * v; }
    __shared__ double sh_s[256], sh_ss[256];
    sh_s[threadIdx.x] = s; sh_ss[threadIdx.x] = ss; __syncthreads();
    for (int off = 128; off > 0; off >>= 1) {
        if (threadIdx.x < off) { sh_s[threadIdx.x] += sh_s[threadIdx.x + off];
                                 sh_ss[threadIdx.x] += sh_ss[threadIdx.x + off]; }
        __syncthreads();
    }
    if (threadIdx.x == 0) {
        double mean = sh_s[0] / N;
        double var = (sh_ss[0] - mean * sh_s[0]) / (N - 1);
        if (var < 0.0) var = 0.0;
        stats[r] = 1.0f / ((float)sqrt(var) + 0.01f);
    }
}

// W[i,j] = exp(-max(sq_i+sq_j-2<xi,xj>,0)/10)  -> bf16, + f32 row partials
__global__ __launch_bounds__(256) void k_we(const float* __restrict__ X,
                                            const float* __restrict__ stats,
                                            ushort* __restrict__ W,
                                            float* __restrict__ part, int N) {
    int i = blockIdx.y, t = threadIdx.x;
    int NB = gridDim.x;
    int j = blockIdx.x * 1024 + t * 4;
    float s0 = stats[0], s1 = stats[1], s2 = stats[2];
    float a0 = X[i] * s0, a1 = X[N + i] * s1, a2 = X[2 * N + i] * s2;
    float si = a0 * a0 + a1 * a1 + a2 * a2;
    float psum = 0.f;
    if (j < N) {
        float4 x0 = *(const float4*)(X + j);
        float4 x1 = *(const float4*)(X + N + j);
        float4 x2 = *(const float4*)(X + 2 * N + j);
        float4 wv;
        float b0, b1, b2, sj, D;
        b0 = x0.x * s0; b1 = x1.x * s1; b2 = x2.x * s2; sj = b0*b0+b1*b1+b2*b2;
        D = fmaxf(si + sj - 2.f*(a0*b0 + a1*b1 + a2*b2), 0.f);
        wv.x = exp2f(-D * 0.14426950408889634f);
        b0 = x0.y * s0; b1 = x1.y * s1; b2 = x2.y * s2; sj = b0*b0+b1*b1+b2*b2;
        D = fmaxf(si + sj - 2.f*(a0*b0 + a1*b1 + a2*b2), 0.f);
        wv.y = exp2f(-D * 0.14426950408889634f);
        b0 = x0.z * s0; b1 = x1.z * s1; b2 = x2.z * s2; sj = b0*b0+b1*b1+b2*b2;
        D = fmaxf(si + sj - 2.f*(a0*b0 + a1*b1 + a2*b2), 0.f);
        wv.z = exp2f(-D * 0.14426950408889634f);
        b0 = x0.w * s0; b1 = x1.w * s1; b2 = x2.w * s2; sj = b0*b0+b1*b1+b2*b2;
        D = fmaxf(si + sj - 2.f*(a0*b0 + a1*b1 + a2*b2), 0.f);
        wv.w = exp2f(-D * 0.14426950408889634f);
        *(ushort4*)(W + (size_t)i * N + j) =
            make_ushort4(f2b(wv.x), f2b(wv.y), f2b(wv.z), f2b(wv.w));
        psum = wv.x + wv.y + wv.z + wv.w;
    }
    __shared__ float red[256];
    red[t] = psum; __syncthreads();
    for (int off = 128; off > 0; off >>= 1) {
        if (t < off) red[t] += red[t + off];
        __syncthreads();
    }
    if (t == 0) part[(size_t)i * NB + blockIdx.x] = red[0];
}

// L[i,j] = M_i*M_j*((i==j)?d_i:0 - W[i,j]) + (i==j)*(1-M_j), bf16 in place
__global__ __launch_bounds__(256) void k_finalize(ushort* __restrict__ W,
                                                  const float* __restrict__ part,
                                                  const float* __restrict__ m, int N, int NB) {
    int i = blockIdx.y;
    int j = blockIdx.x * 1024 + threadIdx.x * 4;
    float d = 0.f;
    for (int k = 0; k < NB; k++) d += part[(size_t)i * NB + k];
    float mi = m[i];
    if (j < N) {
        ushort4 wb = *(const ushort4*)(W + (size_t)i * N + j);
        float4 w = make_float4(b2f(wb.x), b2f(wb.y), b2f(wb.z), b2f(wb.w));
        float4 mj = *(const float4*)(m + j);
        float lv;
        float4 o;
        lv = ((j + 0 == i) ? d : 0.f) - w.x; lv = mi * mj.x * lv; if (j + 0 == i) lv += 1.f - mj.x; o.x = lv;
        lv = ((j + 1 == i) ? d : 0.f) - w.y; lv = mi * mj.y * lv; if (j + 1 == i) lv += 1.f - mj.y; o.y = lv;
        lv = ((j + 2 == i) ? d : 0.f) - w.z; lv = mi * mj.z * lv; if (j + 2 == i) lv += 1.f - mj.z; o.z = lv;
        lv = ((j + 3 == i) ? d : 0.f) - w.w; lv = mi * mj.w * lv; if (j + 3 == i) lv += 1.f - mj.w; o.w = lv;
        *(ushort4*)(W + (size_t)i * N + j) =
            make_ushort4(f2b(o.x), f2b(o.y), f2b(o.z), f2b(o.w));
    }
}

// ---------- MFMA GEMM: y[c,j] = sum_k x[c,k] * L[k,j];  L symmetric bf16 ----------
// A frag: lane row=l&15, k=(l>>4)*8+i (contiguous row of xb)
// B frag: B[k][j] = L[j][k] (symmetry) -> contiguous row of Lb
// D: row=(l>>4)*4+r, col=l&15
template<int CT>
__global__ __launch_bounds__(256) void k_mmf(const ushort* __restrict__ xb,
                                             const ushort* __restrict__ Lb,
                                             float* __restrict__ yp, int N, int chunk) {
    int t = threadIdx.x;
    int w = t >> 6, l = t & 63;
    int j0 = blockIdx.x * 64 + w * 16;
    int lrow = l & 15, lk = l >> 4;
    size_t kbase = (size_t)blockIdx.z * chunk + lk * 8;
    f32x4 acc[CT];
    #pragma unroll
    for (int cc = 0; cc < CT; cc++) acc[cc] = (f32x4){0.f, 0.f, 0.f, 0.f};
    const ushort* bp = Lb + (size_t)(j0 + lrow) * N + kbase;
    const ushort* ap = xb + (size_t)lrow * N + kbase;
    for (int k0 = 0; k0 < chunk; k0 += 32) {
        bf16x8 b = *(const bf16x8*)(bp); bp += 32;
        #pragma unroll
        for (int cc = 0; cc < CT; cc++) {
            bf16x8 a = *(const bf16x8*)(ap + (size_t)cc * 16 * N + k0);
            acc[cc] = __builtin_amdgcn_mfma_f32_16x16x32_bf16(a, b, acc[cc], 0, 0, 0);
        }
    }
    float* yo = yp + (size_t)blockIdx.z * (CT * 16) * N;
    #pragma unroll
    for (int cc = 0; cc < CT; cc++) {
        #pragma unroll
        for (int r = 0; r < 4; r++)
            yo[(size_t)(cc * 16 + lk * 4 + r) * N + j0 + lrow] = acc[cc][r];
    }
}

__global__ __launch_bounds__(256) void k_reduce(const float* __restrict__ yp,
                                                float* __restrict__ y, int parts, size_t total) {
    size_t idx = (size_t)blockIdx.x * 256 + threadIdx.x;
    if (idx >= total) return;
    float s = 0.f;
    for (int p = 0; p < parts; p++) s += yp[(size_t)p * total + idx];
    y[idx] = s;
}

// ---------- conv phase A: partial 9-tap conv, 4 cols/thread ----------
// grid (Cout*N/1024, 1, KS); chunk = Cin/KS channels per z-slice.
__global__ __launch_bounds__(256) void k_convA2(const float* __restrict__ y,
                                                const float* __restrict__ Kw,
                                                float* __restrict__ zp,
                                                int C_in, int C_out, int N, int nshift,
                                                int chunk, int transpose) {
    __shared__ float wsm[2][64][9];
    int t = threadIdx.x;
    int bx = blockIdx.x;
    int ic0 = blockIdx.z * chunk;
    int o0 = (bx << 10) >> nshift;
    int CPB = (N < 1024) ? 2 : 1;

    for (int idx = t; idx < CPB * chunk * 9; idx += 256) {
        int oo = idx / (chunk * 9);
        int rem = idx - oo * chunk * 9;
        int ii = rem / 9, tap = rem - ii * 9;
        int o = o0 + oo;
        float wv;
        if (!transpose) wv = Kw[((size_t)o * C_in + ic0 + ii) * 9 + tap];
        else            wv = Kw[((size_t)(ic0 + ii) * C_out + o) * 9 + (8 - tap)];
        wsm[oo][ii][tap] = wv;
    }
    __syncthreads();

    int flat = (bx << 10) + t * 4;
    int o = flat >> nshift;
    int col = flat & (N - 1);
    int ol = o - o0;
    bool interior = (col >= 4) && (col + 8 <= N);
    float a0 = 0.f, a1 = 0.f, a2 = 0.f, a3 = 0.f;

    for (int ii = 0; ii < chunk; ii++) {
        const float* yr = y + (size_t)(ic0 + ii) * N;
        float f[12];
        if (interior) {
            float4 v0 = *(const float4*)(yr + col - 4);
            float4 v1 = *(const float4*)(yr + col);
            float4 v2 = *(const float4*)(yr + col + 4);
            f[0]=v0.x; f[1]=v0.y; f[2]=v0.z; f[3]=v0.w;
            f[4]=v1.x; f[5]=v1.y; f[6]=v1.z; f[7]=v1.w;
            f[8]=v2.x; f[9]=v2.y; f[10]=v2.z; f[11]=v2.w;
        } else {
            #pragma unroll
            for (int q = 0; q < 12; q++) {
                int c = col - 4 + q;
                f[q] = (c >= 0 && c < N) ? yr[c] : 0.f;
            }
        }
        const float* wt = wsm[ol][ii];
        #pragma unroll
        for (int tp = 0; tp < 9; tp++) {
            float wv = wt[tp];
            a0 += f[tp] * wv; a1 += f[tp + 1] * wv;
            a2 += f[tp + 2] * wv; a3 += f[tp + 3] * wv;
        }
    }
    *(float4*)(zp + ((size_t)blockIdx.z * C_out + o) * N + col) = make_float4(a0, a1, a2, a3);
}

// ---------- conv phase B: merge partials + mask + block IN stats ----------
__global__ __launch_bounds__(256) void k_convB(const float* __restrict__ zp,
                                               const float* __restrict__ m,
                                               float* __restrict__ zm,
                                               float2* __restrict__ sp,
                                               int C_out, int N, int KS) {
    int o = blockIdx.y;
    int t = threadIdx.x;
    int NB = gridDim.x;
    int base = blockIdx.x * 512 + t * 2;
    float z0 = 0.f, z1 = 0.f;
    for (int p = 0; p < KS; p++) {
        float2 v = *(const float2*)(zp + ((size_t)p * C_out + o) * N + base);
        z0 += v.x; z1 += v.y;
    }
    float2 mv = *(const float2*)(m + base);
    z0 *= mv.x; z1 *= mv.y;
    *(float2*)(zm + (size_t)o * N + base) = make_float2(z0, z1);

    __shared__ float red[256], red2[256];
    red[t] = z0 + z1; red2[t] = z0 * z0 + z1 * z1;
    __syncthreads();
    for (int off = 128; off > 0; off >>= 1) {
        if (t < off) { red[t] += red[t + off]; red2[t] += red2[t + off]; }
        __syncthreads();
    }
    if (t == 0) sp[(size_t)o * NB + blockIdx.x] = make_float2(red[0], red2[0]);
}

// ---------- conv phase C: IN apply + relu + residual (+ bf16 shadow) ----------
__global__ __launch_bounds__(256) void k_convC(const float* __restrict__ zm,
                                               const float2* __restrict__ sp,
                                               const float* __restrict__ res,
                                               float* __restrict__ xout,
                                               ushort* __restrict__ xob, int N, int NB) {
    int o = blockIdx.y;
    int t = threadIdx.x;
    int base = blockIdx.x * 512 + t * 2;
    float s = 0.f, ss = 0.f;
    for (int k = 0; k < NB; k++) { float2 p = sp[(size_t)o * NB + k]; s += p.x; ss += p.y; }
    float mean = s / N;
    float var = fmaxf(ss / N - mean * mean, 0.f);
    float rs = rsqrtf(var + 1e-5f);
    float2 z = *(const float2*)(zm + (size_t)o * N + base);
    float v0 = fmaxf((z.x - mean) * rs, 0.f);
    float v1 = fmaxf((z.y - mean) * rs, 0.f);
    if (res) {
        float2 r = *(const float2*)(res + (size_t)o * N + base);
        v0 += r.x; v1 += r.y;
    }
    *(float2*)(xout + (size_t)o * N + base) = make_float2(v0, v1);
    if (xob) *(ushort2*)(xob + (size_t)o * N + base) = make_ushort2(f2b(v0), f2b(v1));
}

// ---------- fused pool (z rows + mask + X), z dual-written bf16 ----------
__global__ __launch_bounds__(256) void k_poolall(const float* __restrict__ z_in,
                                                 float* __restrict__ z_out,
                                                 ushort* __restrict__ zb_out, int Cz,
                                                 const float* __restrict__ m_in, float* __restrict__ m_out,
                                                 const float* __restrict__ X_in, float* __restrict__ X_out, int Nin) {
    int No = Nin >> 1;
    int idx = blockIdx.x * 256 + threadIdx.x;
    int total = (Cz + 4) * No;
    if (idx >= total) return;
    int r = idx / No, ii = idx - r * No;
    const float* src;
    if (r < Cz) {
        src = z_in + (size_t)r * Nin;
        float a = (ii > 0) ? src[2 * ii - 1] : 0.f;
        float v = (a + src[2 * ii] + src[2 * ii + 1]) * (1.f / 3.f);
        z_out[(size_t)r * No + ii] = v;
        zb_out[(size_t)r * No + ii] = f2b(v);
    } else if (r == Cz) {
        src = m_in;
        float a = (ii > 0) ? src[2 * ii - 1] : 0.f;
        m_out[ii] = (a + src[2 * ii] + src[2 * ii + 1]) * (1.f / 3.f);
    } else {
        src = X_in + (size_t)(r - Cz - 1) * Nin;
        float a = (ii > 0) ? src[2 * ii - 1] : 0.f;
        X_out[(size_t)(r - Cz - 1) * No + ii] = (a + src[2 * ii] + src[2 * ii + 1]) * (1.f / 3.f);
    }
}

__global__ __launch_bounds__(256) void k_repeat(const float* __restrict__ in,
                                                float* __restrict__ out,
                                                ushort* __restrict__ outb, int rows, int Nin) {
    int idx = blockIdx.x * 256 + threadIdx.x;
    if (idx >= rows * Nin) return;
    int r = idx / Nin, i = idx - r * Nin;
    float v = in[(size_t)r * Nin + i];
    size_t o = (size_t)r * 2 * Nin + 2 * i;
    out[o] = v; out[o + 1] = v;
    ushort h = f2b(v);
    outb[o] = h; outb[o + 1] = h;
}

__global__ __launch_bounds__(256) void k_cast(const float* __restrict__ in,
                                              ushort* __restrict__ out, int n) {
    int i = (blockIdx.x * 256 + threadIdx.x) * 4;
    if (i >= n) return;
    float4 v = *(const float4*)(in + i);
    *(ushort4*)(out + i) = make_ushort4(f2b(v.x), f2b(v.y), f2b(v.z), f2b(v.w));
}

// ---------- host ----------

extern "C" void kernel_launch(void* const* d_in, const int* in_sizes, int n_in,
                              void* d_out, int out_size, void* d_ws, size_t ws_size,
                              hipStream_t stream) {
    (void)in_sizes; (void)n_in; (void)out_size; (void)ws_size;
    const float* x_in = (const float*)d_in[0];
    const float* X0 = (const float*)d_in[1];
    const float* m0 = (const float*)d_in[2];
    const float* Kw[11];
    for (int i = 0; i < 11; i++) Kw[i] = (const float*)d_in[3 + i];
    float* out = (float*)d_out;
    float* ws = (float*)d_ws;

    const int Ns[4] = {4096, 2048, 1024, 512};

    size_t off = 0;
    auto alloc = [&](size_t n) { float* p = ws + off; off += (n + 63) & ~(size_t)63; return p; };
    // bf16 Laplacians (allocated in float units = 2 ushorts each)
    ushort* Lb[4];
    Lb[0] = (ushort*)alloc(8388608); Lb[1] = (ushort*)alloc(2097152);
    Lb[2] = (ushort*)alloc(524288);  Lb[3] = (ushort*)alloc(131072);
    float* part = alloc(16384);
    float* stats = alloc(64);
    float* spbuf = alloc(1024);
    float* zmbuf = alloc(262144);
    float* mlev[4];
    mlev[0] = const_cast<float*>(m0);
    mlev[1] = alloc(2048); mlev[2] = alloc(1024); mlev[3] = alloc(512);
    float* Xlev[4];
    Xlev[0] = const_cast<float*>(X0);
    Xlev[1] = alloc(3 * 2048); Xlev[2] = alloc(3 * 1024); Xlev[3] = alloc(3 * 512);
    float* pA[4], *pB[4], *xs[3];
    for (int l = 0; l < 4; l++) { pA[l] = alloc(131072); pB[l] = alloc(131072); }
    for (int l = 0; l < 3; l++) xs[l] = alloc(131072);
    float* zbig = alloc(262144);
    float* ybuf = alloc(262144);
    float* yp = alloc(4194304);   // shared partials: matmul split-K and conv split-C
    // bf16 shadows
    ushort* xinb = (ushort*)alloc(65536);
    ushort* pAb[4], *pBb[4], *xsb[3];
    for (int l = 0; l < 4; l++) { pAb[l] = (ushort*)alloc(65536); pBb[l] = (ushort*)alloc(65536); }
    for (int l = 0; l < 3; l++) xsb[l] = (ushort*)alloc(65536);
    ushort* zbigb = (ushort*)alloc(131072);

    auto build_lap = [&](int lvl) {
        int N = Ns[lvl];
        int NB = N / 1024 > 0 ? N / 1024 : 1;
        k_rowstats<<<3, 256, 0, stream>>>(Xlev[lvl], N, stats);
        k_we<<<dim3(NB, N), 256, 0, stream>>>(Xlev[lvl], stats, Lb[lvl], part, N);
        k_finalize<<<dim3(NB, N), 256, 0, stream>>>(Lb[lvl], part, mlev[lvl], N, NB);
    };

    auto matmul = [&](const ushort* xbv, int C, int lvl, float* yout) {
        int N = Ns[lvl];
        int ks = (lvl == 0) ? 8 : 16;
        int chunk = N / ks;
        dim3 g(N / 64, 1, ks);
        if (C == 32)       k_mmf<2><<<g, 256, 0, stream>>>(xbv, Lb[lvl], yp, N, chunk);
        else if (C == 64)  k_mmf<4><<<g, 256, 0, stream>>>(xbv, Lb[lvl], yp, N, chunk);
        else if (C == 128) k_mmf<8><<<g, 256, 0, stream>>>(xbv, Lb[lvl], yp, N, chunk);
        else               k_mmf<16><<<g, 256, 0, stream>>>(xbv, Lb[lvl], yp, N, chunk);
        size_t total = (size_t)C * N;
        k_reduce<<<(unsigned)((total + 255) / 256), 256, 0, stream>>>(yp, yout, ks, total);
    };

    auto conv = [&](const float* yv, const float* Kv, int lvl, const float* resv,
                    float* ov, ushort* ovb, int Cin, int Cout, int tr) {
        int N = Ns[lvl];
        int nshift = 31 - __builtin_clz((unsigned)N);
        int bx = Cout * N / 1024;
        int KS = 1;
        while (KS * 2 <= Cin / 16 && bx * KS < 512) KS <<= 1;
        int chunk = Cin / KS;
        k_convA2<<<dim3(bx, 1, KS), 256, 0, stream>>>(yv, Kv, yp, Cin, Cout, N, nshift, chunk, tr);
        int NBb = N / 512;
        k_convB<<<dim3(NBb, Cout), 256, 0, stream>>>(yp, mlev[lvl], zmbuf, (float2*)spbuf, Cout, N, KS);
        k_convC<<<dim3(NBb, Cout), 256, 0, stream>>>(zmbuf, (const float2*)spbuf, resv, ov, ovb, N, NBb);
    };

    auto poolall = [&](const float* z_in, float* z_out, ushort* zb_out, int Cz, int lvl_from) {
        int Nin = Ns[lvl_from];
        int No = Nin >> 1;
        int total = (Cz + 4) * No;
        k_poolall<<<(total + 255) / 256, 256, 0, stream>>>(z_in, z_out, zb_out, Cz,
                                                           mlev[lvl_from], mlev[lvl_from + 1],
                                                           Xlev[lvl_from], Xlev[lvl_from + 1], Nin);
    };

    k_cast<<<(32 * 4096) / 1024, 256, 0, stream>>>(x_in, xinb, 32 * 4096);

    // ---- down ----
    build_lap(0);
    matmul(xinb, 32, 0, ybuf);   conv(ybuf, Kw[0], 0, x_in, pA[0], pAb[0], 32, 32, 0);
    matmul(pAb[0], 32, 0, ybuf); conv(ybuf, Kw[1], 0, pA[0], xs[0], xsb[0], 32, 32, 0);
    matmul(xsb[0], 32, 0, ybuf); conv(ybuf, Kw[2], 0, nullptr, zbig, nullptr, 32, 64, 0);
    poolall(zbig, pA[1], pAb[1], 64, 0);
    build_lap(1);
    matmul(pAb[1], 64, 1, ybuf); conv(ybuf, Kw[3], 1, pA[1], pB[1], pBb[1], 64, 64, 0);
    matmul(pBb[1], 64, 1, ybuf); conv(ybuf, Kw[4], 1, pB[1], xs[1], xsb[1], 64, 64, 0);
    matmul(xsb[1], 64, 1, ybuf); conv(ybuf, Kw[5], 1, nullptr, zbig, nullptr, 64, 128, 0);
    poolall(zbig, pA[2], pAb[2], 128, 1);
    build_lap(2);
    matmul(pAb[2], 128, 2, ybuf); conv(ybuf, Kw[6], 2, pA[2], pB[2], pBb[2], 128, 128, 0);
    matmul(pBb[2], 128, 2, ybuf); conv(ybuf, Kw[7], 2, pB[2], xs[2], xsb[2], 128, 128, 0);
    matmul(xsb[2], 128, 2, ybuf); conv(ybuf, Kw[8], 2, nullptr, zbig, nullptr, 128, 256, 0);
    poolall(zbig, pA[3], pAb[3], 256, 2);
    build_lap(3);
    matmul(pAb[3], 256, 3, ybuf); conv(ybuf, Kw[9], 3, pA[3], pB[3], pBb[3], 256, 256, 0);
    matmul(pBb[3], 256, 3, ybuf); conv(ybuf, Kw[10], 3, pB[3], pA[3], pAb[3], 256, 256, 0);

    // ---- up ----
    matmul(pAb[3], 256, 3, ybuf); conv(ybuf, Kw[10], 3, pA[3], pB[3], pBb[3], 256, 256, 1);
    matmul(pBb[3], 256, 3, ybuf); conv(ybuf, Kw[9], 3, pB[3], pA[3], nullptr, 256, 256, 1);

    k_repeat<<<(256 * 512) / 256, 256, 0, stream>>>(pA[3], zbig, zbigb, 256, 512); // -> 256x1024
    matmul(zbigb, 256, 2, ybuf);  conv(ybuf, Kw[8], 2, xs[2], pB[2], pBb[2], 256, 128, 1);
    matmul(pBb[2], 128, 2, ybuf); conv(ybuf, Kw[7], 2, pB[2], pA[2], pAb[2], 128, 128, 1);
    matmul(pAb[2], 128, 2, ybuf); conv(ybuf, Kw[6], 2, pA[2], pB[2], nullptr, 128, 128, 1);

    k_repeat<<<(128 * 1024) / 256, 256, 0, stream>>>(pB[2], zbig, zbigb, 128, 1024); // -> 128x2048
    matmul(zbigb, 128, 1, ybuf);  conv(ybuf, Kw[5], 1, xs[1], pA[1], pAb[1], 128, 64, 1);
    matmul(pAb[1], 64, 1, ybuf);  conv(ybuf, Kw[4], 1, pA[1], pB[1], pBb[1], 64, 64, 1);
    matmul(pBb[1], 64, 1, ybuf);  conv(ybuf, Kw[3], 1, pB[1], pA[1], nullptr, 64, 64, 1);

    k_repeat<<<(64 * 2048) / 256, 256, 0, stream>>>(pA[1], zbig, zbigb, 64, 2048); // -> 64x4096
    matmul(zbigb, 64, 0, ybuf);  conv(ybuf, Kw[2], 0, xs[0], pB[0], pBb[0], 64, 32, 1);
    matmul(pBb[0], 32, 0, ybuf); conv(ybuf, Kw[1], 0, pB[0], pA[0], pAb[0], 32, 32, 1);
    matmul(pAb[0], 32, 0, ybuf); conv(ybuf, Kw[0], 0, pA[0], out, nullptr, 32, 32, 1);
}